// Round 6
// baseline (90.190 us; speedup 1.0000x reference)
//
#include <hip/hip_runtime.h>

#define N_LEAVES  256
#define N_CLASSES 512

typedef float f32x4 __attribute__((ext_vector_type(4)));

// Persistent wave-per-row with 1-deep prefetch pipeline — PLAIN loads/stores
// (isolation of R5: nontemporal hints removed, everything else identical).
//   each of 8192 waves (32/CU) owns rows {gid, gid+8192, ...} (16 rows).
//   Per iteration: issue next row's weight load FIRST, then argmax/gather/
//   store the current row -> next load's HBM latency hides under the
//   current row's shuffle chain + L2 gather + store.
__global__ __launch_bounds__(256) void OutputLayer_41961830482215_kernel(
    const float* __restrict__ opinions,
    const float* __restrict__ weights,
    float* __restrict__ out,
    int batch)
{
    const int wave = threadIdx.x >> 6;
    const int lane = threadIdx.x & 63;
    const long long W   = (long long)gridDim.x * 4;        // total waves
    const long long gid = (long long)blockIdx.x * 4 + wave;

    long long row = gid;
    if (row >= batch) return;

    // prologue: load first row's weights
    f32x4 w_next = *(reinterpret_cast<const f32x4*>(weights + row * N_LEAVES) + lane);

    while (row < batch) {
        const f32x4 w = w_next;
        const long long nrow = row + W;
        if (nrow < batch) {
            // issue next row's load before the dependent chain below
            w_next = *(reinterpret_cast<const f32x4*>(weights + nrow * N_LEAVES) + lane);
        }

        // ---- argmax over this row's 256 weights ----
        float best = w.x;
        int   bidx = lane * 4;
        if (w.y > best) { best = w.y; bidx = lane * 4 + 1; }
        if (w.z > best) { best = w.z; bidx = lane * 4 + 2; }
        if (w.w > best) { best = w.w; bidx = lane * 4 + 3; }
        #pragma unroll
        for (int off = 32; off >= 1; off >>= 1) {
            const float ov = __shfl_xor(best, off);
            const int   oi = __shfl_xor(bidx, off);
            if (ov > best || (ov == best && oi < bidx)) { best = ov; bidx = oi; }
        }

        // ---- gather opinions[bidx] (L2-resident) -> out[row] ----
        const f32x4* __restrict__ src =
            reinterpret_cast<const f32x4*>(opinions + (long long)bidx * N_CLASSES);
        const f32x4 lo = src[lane];
        const f32x4 hi = src[lane + 64];
        f32x4* dst = reinterpret_cast<f32x4*>(out + row * N_CLASSES);
        dst[lane]      = lo;
        dst[lane + 64] = hi;

        row = nrow;
    }
}

extern "C" void kernel_launch(void* const* d_in, const int* in_sizes, int n_in,
                              void* d_out, int out_size, void* d_ws, size_t ws_size,
                              hipStream_t stream) {
    const float* opinions = (const float*)d_in[0];   // [256, 512]
    const float* weights  = (const float*)d_in[1];   // [batch, 256]
    float* out = (float*)d_out;                      // [batch, 512]
    const int batch = in_sizes[1] / N_LEAVES;

    // 2048 blocks x 4 waves = 8192 waves = 32 waves/CU on 256 CUs.
    int blocks = 2048;
    const int max_blocks = (batch + 3) / 4;          // never more waves than rows
    if (blocks > max_blocks) blocks = max_blocks;
    OutputLayer_41961830482215_kernel<<<blocks, 256, 0, stream>>>(
        opinions, weights, out, batch);
}

// Round 7
// 77.731 us; speedup vs baseline: 1.1603x; 1.1603x over previous
//
#include <hip/hip_runtime.h>

#define N_LEAVES  256
#define N_CLASSES 512

typedef float f32x4 __attribute__((ext_vector_type(4)));

// EXACT resubmission of the round-1 best kernel (79.2 us) as a
// reproducibility control. One 64-lane wave per batch row:
//   phase 1: wave-parallel argmax over the row's 256 weights (f32x4/lane,
//            shfl_xor butterfly, first-occurrence tie-break like jnp.argmax)
//   phase 2: wave copies opinions[idx] (512 f32 = 2 KiB) to out row,
//            2x f32x4 per lane. opinions is 512 KiB total -> L2-resident.
__global__ __launch_bounds__(256) void OutputLayer_41961830482215_kernel(
    const float* __restrict__ opinions,
    const float* __restrict__ weights,
    float* __restrict__ out,
    int batch)
{
    const int wave = threadIdx.x >> 6;   // 0..3
    const int lane = threadIdx.x & 63;
    const long long row = (long long)blockIdx.x * 4 + wave;
    if (row >= batch) return;

    // ---- argmax over 256 weights of this row ----
    const f32x4 w = *(reinterpret_cast<const f32x4*>(weights + row * N_LEAVES) + lane);
    float best = w.x;
    int   bidx = lane * 4;
    if (w.y > best) { best = w.y; bidx = lane * 4 + 1; }
    if (w.z > best) { best = w.z; bidx = lane * 4 + 2; }
    if (w.w > best) { best = w.w; bidx = lane * 4 + 3; }

    // butterfly reduce across 64 lanes; prefer lower index on ties
    #pragma unroll
    for (int off = 32; off >= 1; off >>= 1) {
        const float ov = __shfl_xor(best, off);
        const int   oi = __shfl_xor(bidx, off);
        if (ov > best || (ov == best && oi < bidx)) { best = ov; bidx = oi; }
    }
    // all 64 lanes now agree on bidx

    // ---- gather opinions[bidx] -> out[row] ----
    const f32x4* __restrict__ src =
        reinterpret_cast<const f32x4*>(opinions + (long long)bidx * N_CLASSES);
    f32x4* __restrict__ dst =
        reinterpret_cast<f32x4*>(out + row * N_CLASSES);
    dst[lane]      = src[lane];        // floats [0..255]
    dst[lane + 64] = src[lane + 64];   // floats [256..511]
}

extern "C" void kernel_launch(void* const* d_in, const int* in_sizes, int n_in,
                              void* d_out, int out_size, void* d_ws, size_t ws_size,
                              hipStream_t stream) {
    const float* opinions = (const float*)d_in[0];   // [256, 512]
    const float* weights  = (const float*)d_in[1];   // [batch, 256]
    float* out = (float*)d_out;                      // [batch, 512]
    const int batch = in_sizes[1] / N_LEAVES;
    const int blocks = (batch + 3) / 4;              // 4 rows per 256-thread block
    OutputLayer_41961830482215_kernel<<<blocks, 256, 0, stream>>>(
        opinions, weights, out, batch);
}